// Round 11
// baseline (503.756 us; speedup 1.0000x reference)
//
#include <hip/hip_runtime.h>

#define DEV_INLINE __device__ __forceinline__

typedef int i32x4 __attribute__((ext_vector_type(4)));
typedef int i32x16 __attribute__((ext_vector_type(16)));

DEV_INLINE int dot4(int a, int b, int c) {
#if __has_builtin(__builtin_amdgcn_sdot4)
    return __builtin_amdgcn_sdot4(a, b, c, false);
#else
    return c
        + (int)(signed char)(a)       * (int)(signed char)(b)
        + (int)(signed char)(a >> 8)  * (int)(signed char)(b >> 8)
        + (int)(signed char)(a >> 16) * (int)(signed char)(b >> 16)
        + (int)(signed char)(a >> 24) * (int)(signed char)(b >> 24);
#endif
}

typedef __attribute__((address_space(1))) const unsigned int guint;
typedef __attribute__((address_space(3))) unsigned int luint;

// async 16B/lane global->LDS DMA: lane i's 16B from g+lane*16 lands at l+lane*16
DEV_INLINE void async_cp16(const signed char* g, signed char* l) {
    __builtin_amdgcn_global_load_lds((guint*)g, (luint*)l, 16, 0, 0);
}

// counted-vmcnt barrier: wait until <=N vector-memory ops outstanding, then s_barrier.
template <int N>
DEV_INLINE void wait_barrier() {
    __builtin_amdgcn_sched_barrier(0);
    asm volatile("s_waitcnt vmcnt(%0)" :: "n"(N) : "memory");
    __builtin_amdgcn_s_barrier();
    __builtin_amdgcn_sched_barrier(0);
}

// ---------------- fused weight/bias conversion (single launch, ws-cached) ----------------

#define CVT_MAGIC 0x9E3779B97F4A7C15ull

// Repack to 32-wide MFMA B-fragment-major order, K reordered tap-major:
//   step = tap*CP + cpair;  lane holds B[n = oc%32][element c = cpair*32 + (lane>>5)*16 + j of tap]
DEV_INLINE void cvt_frag32_elem(const float* __restrict__ w, signed char* __restrict__ o,
                                int idx, int I, int KK, int CP, int KSTEPS) {
    int j = idx & 15;
    int lane = (idx >> 4) & 63;
    int step = (idx >> 10) % KSTEPS;
    int tile = idx / (KSTEPS << 10);
    int oc = tile * 32 + (lane & 31);
    int tap = step / CP;
    int cpair = step - tap * CP;
    int c = cpair * 32 + ((lane >> 5) << 4) + j;
    o[idx] = (signed char)(int)w[((size_t)oc * I + c) * KK + tap];
}

struct CvtArgs {
    const float *w1, *w2, *w3, *w4, *w5, *wf1, *wf2, *wf3;
    const float *b1, *b2, *b3, *b4, *b5, *bf1, *bf2, *bf3;
    signed char *W1, *W2, *W3, *W4, *W5, *WF1, *WF2, *WF3;
    int *B1, *B2, *B3, *B4, *B5, *BF1, *BF2, *BF3;
    const unsigned long long* flag;
};

#define SZ_W2  (8 * 75 * 1024)
#define SZ_W3  (12 * 72 * 1024)
#define SZ_W4  (12 * 108 * 1024)
#define SZ_W5  (8 * 108 * 1024)
#define SZ_WF1 (128 * 8 * 1024)
#define SZ_WF2 (128 * 128 * 1024)
#define SZ_WF3 (10 * 4096)
#define SZ_W1  (96 * 128)
#define SZ_BIAS (96 + 256 + 384 + 384 + 256 + 4096 + 4096 + 10)
#define CVT_TOTAL (SZ_WF2 + SZ_W4 + SZ_WF1 + SZ_W3 + SZ_W5 + SZ_W2 + SZ_WF3 + SZ_W1 + SZ_BIAS)

DEV_INLINE void cvt_one(const CvtArgs& a, int idx) {
    if (idx < SZ_WF2) { cvt_frag32_elem(a.wf2, a.WF2, idx, 4096, 1, 128, 128); return; }
    idx -= SZ_WF2;
    if (idx < SZ_W4) { cvt_frag32_elem(a.w4, a.W4, idx, 384, 9, 12, 108); return; }
    idx -= SZ_W4;
    if (idx < SZ_WF1) { cvt_frag32_elem(a.wf1, a.WF1, idx, 256, 1, 8, 8); return; }
    idx -= SZ_WF1;
    if (idx < SZ_W3) { cvt_frag32_elem(a.w3, a.W3, idx, 256, 9, 8, 72); return; }
    idx -= SZ_W3;
    if (idx < SZ_W5) { cvt_frag32_elem(a.w5, a.W5, idx, 384, 9, 12, 108); return; }
    idx -= SZ_W5;
    if (idx < SZ_W2) { cvt_frag32_elem(a.w2, a.W2, idx, 96, 25, 3, 75); return; }
    idx -= SZ_W2;
    if (idx < SZ_WF3) { a.WF3[idx] = (signed char)(int)a.wf3[idx]; return; }
    idx -= SZ_WF3;
    if (idx < SZ_W1) {
        // conv1 weights: OIHW [96][3][5][5] fp32 -> [96][128] int8, byte [oc][tap*4+c]
        int b = idx & 127;
        int oc = idx >> 7;
        int tap = b >> 2;
        int c = b & 3;
        float v = (tap < 25 && c < 3) ? a.w1[(oc * 3 + c) * 25 + tap] : 0.0f;
        a.W1[idx] = (signed char)(int)v;
        return;
    }
    idx -= SZ_W1;
    if (idx < 96) { a.B1[idx] = (int)a.b1[idx]; return; } idx -= 96;
    if (idx < 256) { a.B2[idx] = (int)a.b2[idx]; return; } idx -= 256;
    if (idx < 384) { a.B3[idx] = (int)a.b3[idx]; return; } idx -= 384;
    if (idx < 384) { a.B4[idx] = (int)a.b4[idx]; return; } idx -= 384;
    if (idx < 256) { a.B5[idx] = (int)a.b5[idx]; return; } idx -= 256;
    if (idx < 4096) { a.BF1[idx] = (int)a.bf1[idx]; return; } idx -= 4096;
    if (idx < 4096) { a.BF2[idx] = (int)a.bf2[idx]; return; } idx -= 4096;
    if (idx < 10) { a.BF3[idx] = (int)a.bf3[idx]; }
}

// grid-stride: cheap early-exit when the ws cache flag is valid
__global__ void cvt_all(CvtArgs a) {
    if (*a.flag == CVT_MAGIC) return;
    int stride = gridDim.x * blockDim.x;
    for (int idx = blockIdx.x * blockDim.x + threadIdx.x; idx < CVT_TOTAL; idx += stride)
        cvt_one(a, idx);
}

__global__ void set_flag(unsigned long long* f) { *f = CVT_MAGIC; }

// ---------------- quantize input: NCHW fp32 [512,3,32,32] -> NHWC int8 [512,32,32,4] ----------------

__global__ void quantize_in(const float* __restrict__ x, signed char* __restrict__ q, int total) {
    int idx = blockIdx.x * blockDim.x + threadIdx.x;
    if (idx >= total) return;                 // total = 512*32*32
    int hw = idx & 1023;
    int n = idx >> 10;
    const float* xp = x + n * 3072 + hw;
    int b[4];
#pragma unroll
    for (int c = 0; c < 3; ++c) {
        float v = rintf(xp[c * 1024] / 0.05f);
        v = fminf(fmaxf(v, -128.0f), 127.0f);
        b[c] = (int)v;
    }
    b[3] = 0;
    int packed = (b[0] & 0xff) | ((b[1] & 0xff) << 8) | ((b[2] & 0xff) << 16) | (b[3] << 24);
    ((int*)q)[idx] = packed;
}

// ---------------- conv1 MFMA with LDS im2col (16x16x64 path, Cin=4) ----------------
// Site stride padded 36 -> 37 dwords: odd multiplier makes both the 8x b32 writes and
// the 4x b32 reads exactly 2-way bank-aliased (free) instead of 8-way (2.9x).

__global__ void conv1_mfma(const signed char* __restrict__ act,
                           const signed char* __restrict__ wq,
                           const int* __restrict__ bias,
                           signed char* __restrict__ out) {
    __shared__ int lds[64 * 37];                  // 64 sites x 148 B (128 data + 20 pad)

    int tid = threadIdx.x;
    int lane = tid & 63;
    int wid = tid >> 6;
    int siteBase = blockIdx.x * 64;

    {
        int site_local = tid >> 2;
        int g = tid & 3;
        int site = siteBase + site_local;
        int ox = site & 31;
        int oy = (site >> 5) & 31;
        int n = site >> 10;
        const int* aI = (const int*)act;
        int* dst = lds + site_local * 37 + g * 8;
#pragma unroll
        for (int j = 0; j < 8; ++j) {
            int tap = g * 8 + j;
            int v = 0;
            if (tap < 25) {
                int ky = tap / 5;
                int kx = tap - ky * 5;
                int iy = oy - 2 + ky;
                int ix = ox - 2 + kx;
                if ((unsigned)iy < 32u && (unsigned)ix < 32u)
                    v = aI[(n << 10) + (iy << 5) + ix];
            }
            dst[j] = v;
        }
    }

    int m = lane & 15;
    int q = lane >> 4;

    i32x4 bfrag[6][2];
#pragma unroll
    for (int j = 0; j < 6; ++j)
#pragma unroll
        for (int s = 0; s < 2; ++s)
            bfrag[j][s] = *(const i32x4*)(wq + (j * 16 + m) * 128 + s * 64 + q * 16);

    i32x4 acc[6];
#pragma unroll
    for (int j = 0; j < 6; ++j) {
        int bv = bias[j * 16 + m];
        acc[j] = (i32x4){bv, bv, bv, bv};
    }

    __syncthreads();

#pragma unroll
    for (int s = 0; s < 2; ++s) {
        const int* ap = lds + (wid * 16 + m) * 37 + s * 16 + q * 4;
        i32x4 a = (i32x4){ap[0], ap[1], ap[2], ap[3]};
#pragma unroll
        for (int j = 0; j < 6; ++j)
            acc[j] = __builtin_amdgcn_mfma_i32_16x16x64_i8(a, bfrag[j][s], acc[j], 0, 0, 0);
    }

#pragma unroll
    for (int j = 0; j < 6; ++j) {
        int oc = j * 16 + m;
#pragma unroll
        for (int r = 0; r < 4; ++r) {
            int site = siteBase + wid * 16 + q * 4 + r;
            float v = floorf((float)acc[j][r] * 2e-3f);
            v = fminf(fmaxf(v, 0.0f), 127.0f);
            out[(size_t)site * 96 + oc] = (signed char)v;
        }
    }
}

// ---------------- implicit-GEMM 32x32x32 MFMA conv (also FC), LDS-staged B ----------------
// act: NHWC int8 (Cin multiple of 32), wqf: fragment-major [Cout/32][KSTEPS][64][16],
// K tap-major (step = tap*CP + cpair). Block = WAVES waves, ALL sharing one staged B
// range (OCT oc-tiles); each wave owns SITES site-tiles. Groups may be a SUB-TAP slice
// (SUBG = CP/GSTEP slices per tap) to shrink LDS.
//
// DEPTH-2 PREFETCH: triple-buffered LDS; stage(g+2) issued at cp0 of group g, so the
// end-of-g barrier's wait for stage(g+1) has ~2 full groups of MFMA cover. Counted
// waits (in-order vmcnt retirement):
//   NSTEADY = (2*GSTEP-1)*SITES + UNITS/WAVES  (ops younger than stage(g+1)'s DMAs)
//   NTAIL   = (2*GSTEP-1)*SITES                (last staged group: no stage in body)
// Issue order and A-load clamping are byte-identical to the verified round-7 skeleton.
// 8-wave shared-B geometry (conv2-5): B-transit 1024/(WAVES*SITES)=128 B/MFMA,
// A-transit 1024/OCT.

template <int KS, int CIN, int OCT, int SITES, int GSTEP, int WAVES, int MINW>
__launch_bounds__(WAVES * 64, MINW)
__global__ void conv_mfma32(const signed char* __restrict__ act,
                            const signed char* __restrict__ wqf,
                            const int* __restrict__ bias,
                            signed char* __restrict__ out,
                            int H, int W, int OH, int OW, int Cout, int pad, float M) {
    constexpr int CP = CIN / 32;
    constexpr int KSTEPS = KS * KS * CP;
    constexpr int NG = KSTEPS / GSTEP;
    constexpr int SUBG = CP / GSTEP;              // sub-tap slices per tap
    constexpr int CHUNK = OCT * GSTEP * 1024;
    constexpr int UNITS = OCT * GSTEP;
    constexpr int NBUF = (NG >= 3) ? 3 : NG;      // depth-2 prefetch needs 3 buffers
    constexpr int DW = UNITS / WAVES;             // floor: safe lower bound per wave
    constexpr int NSTEADY = (2 * GSTEP - 1) * SITES + DW;
    constexpr int NTAIL = (2 * GSTEP - 1) * SITES;
    constexpr int NPRO = SITES + ((NG > 1) ? DW : 0);
    static_assert(CIN % 32 == 0, "CIN must be multiple of 32");
    static_assert(CP % GSTEP == 0, "GSTEP must divide CP (sub-tap slicing)");
    static_assert(KSTEPS % GSTEP == 0, "GSTEP must divide KSTEPS");
    static_assert(NG != 2, "NG==2 barrier count unsupported");
    static_assert(NSTEADY <= 63, "vmcnt immediate range");

    __shared__ signed char lds[NBUF * CHUNK];

    int lane = threadIdx.x & 63;
    int wid = threadIdx.x >> 6;
    int m32 = lane & 31;
    int q2 = lane >> 5;                           // 0/1: k-half
    int waveBase = blockIdx.x * (SITES * 32 * WAVES) + wid * (SITES * 32);
    int oc0 = blockIdx.y * (OCT * 32);

    const signed char* wblk = wqf + (size_t)(blockIdx.y * OCT) * KSTEPS * 1024;
    const signed char* actq = act + q2 * 16;

    // async-stage group g's B fragments into buffer `buf` (split across WAVES waves)
    auto stage = [&](int buf, int g) {
#pragma unroll
        for (int t = 0; t < (UNITS + WAVES - 1) / WAVES; ++t) {
            int u = t * WAVES + wid;              // 1KB unit: u = j*GSTEP + s
            if (UNITS % WAVES == 0 || u < UNITS) {
                int j = u / GSTEP;
                int s = u - j * GSTEP;
                const signed char* gsrc =
                    wblk + (((size_t)(j * KSTEPS + g * GSTEP + s)) << 10) + lane * 16;
                async_cp16(gsrc, lds + buf * CHUNK + (u << 10));
            }
        }
        __builtin_amdgcn_sched_barrier(0);        // nothing issued later may get older than DMAs
    };

    stage(0, 0);                                  // FIRST vm ops of the kernel

    // per-site-tile coordinate decode (A-side lane site); 32-bit offsets
    int oxA[SITES], oyA[SITES], rbA[SITES];
#pragma unroll
    for (int s = 0; s < SITES; ++s) {
        int site = waveBase + s * 32 + m32;
        int ox = site % OW;
        int t = site / OW;
        oxA[s] = ox;
        oyA[s] = t % OH;
        rbA[s] = (t / OH) * H;
    }

    i32x16 acc[SITES][OCT];
#pragma unroll
    for (int j = 0; j < OCT; ++j) {
        int bv = bias[oc0 + j * 32 + m32];
#pragma unroll
        for (int s = 0; s < SITES; ++s)
#pragma unroll
            for (int r = 0; r < 16; ++r)
                acc[s][j][r] = bv;
    }

    // A-side byte offsets (from actq) + validity for group g (tap = g/SUBG, sub-slice)
    auto calcOff = [&](int g, int* off, bool* ok) {
        int tap = g / SUBG;
        int sub = g - tap * SUBG;
        int ty, tx;
        if constexpr (KS == 1) { ty = 0; tx = 0; }
        else { ty = tap / KS; tx = tap - ty * KS; }
#pragma unroll
        for (int s = 0; s < SITES; ++s) {
            int iy = oyA[s] - pad + ty;
            int ix = oxA[s] - pad + tx;
            if constexpr (KS == 1) ok[s] = true;
            else ok[s] = ((unsigned)iy < (unsigned)H) && ((unsigned)ix < (unsigned)W);
            off[s] = ((rbA[s] + iy) * W + ix) * CIN + sub * (GSTEP * 32);
        }
    };

    // UNCONDITIONAL load (clamped offset, select-zero): vm-op count is compile-time exact
    auto loadA = [&](i32x4* a, const int* off, const bool* ok, int cp) {
#pragma unroll
        for (int s = 0; s < SITES; ++s) {
            int o = ok[s] ? off[s] + cp * 32 : 0;
            i32x4 v = *(const i32x4*)(actq + o);
            a[s] = ok[s] ? v : (i32x4){0, 0, 0, 0};
        }
    };

    int offC[SITES], offN[SITES];
    bool okC[SITES], okN[SITES];
    i32x4 aC[SITES], aN[SITES];
#pragma unroll
    for (int s = 0; s < SITES; ++s) {
        aN[s] = (i32x4){0, 0, 0, 0};
        offN[s] = 0;
        okN[s] = false;
    }

    calcOff(0, offC, okC);
    loadA(aC, offC, okC, 0);                      // SITES loads, younger than stage(0)
    if constexpr (NG > 1) stage(1 % NBUF, 1);     // depth-2 prologue

    wait_barrier<NPRO>();                         // drains stage(0) only

    for (int g = 0; g < NG; ++g) {
        const signed char* lb = lds + (g % NBUF) * CHUNK + lane * 16;
#pragma unroll
        for (int cp = 0; cp < GSTEP; ++cp) {
            // fresh per-cp B fragments (compiler schedules fine-grained lgkm waits)
            i32x4 b[OCT];
#pragma unroll
            for (int j = 0; j < OCT; ++j)
                b[j] = *(const i32x4*)(lb + ((j * GSTEP + cp) << 10));
            // prefetch next A slice: cp0's issue is BEFORE this group's stage DMAs
            if (cp + 1 < GSTEP)
                loadA(aN, offC, okC, cp + 1);
            if (cp == 0) {
                if (g + 2 < NG) stage((g + 2) % NBUF, g + 2);   // 2-group-deep prefetch
                if (g + 1 < NG) calcOff(g + 1, offN, okN);      // VALU, overlaps MFMAs
            }
            if (cp + 1 == GSTEP && g + 1 < NG)
                loadA(aN, offN, okN, 0);          // (g+1, cp0): stays in flight across barrier
#pragma unroll
            for (int j = 0; j < OCT; ++j)
#pragma unroll
                for (int s = 0; s < SITES; ++s)
                    acc[s][j] = __builtin_amdgcn_mfma_i32_32x32x32_i8(aC[s], b[j], acc[s][j], 0, 0, 0);
#pragma unroll
            for (int s = 0; s < SITES; ++s) aC[s] = aN[s];
        }
#pragma unroll
        for (int s = 0; s < SITES; ++s) { offC[s] = offN[s]; okC[s] = okN[s]; }
        if (g + 2 < NG)
            wait_barrier<NSTEADY>();              // stage(g+1) drained; ~2 groups of cover
        else if (g + 1 < NG)
            wait_barrier<NTAIL>();                // last staged group (no stage in body)
    }

    // D layout: col(oc) = lane&31, row(site) = (r&3) + 8*(r>>2) + 4*q2
#pragma unroll
    for (int s = 0; s < SITES; ++s) {
#pragma unroll
        for (int j = 0; j < OCT; ++j) {
            int oc = oc0 + j * 32 + m32;
#pragma unroll
            for (int r = 0; r < 16; ++r) {
                int row = (r & 3) + 8 * (r >> 2) + 4 * q2;
                int site = waveBase + s * 32 + row;
                float v = floorf((float)acc[s][j][r] * M);
                v = fminf(fmaxf(v, 0.0f), 127.0f);
                out[(size_t)site * Cout + oc] = (signed char)v;
            }
        }
    }
}

// ---------------- maxpool 3x3 stride 2, NHWC, 16 channels (i32x4) per thread ----------------

__global__ void qmaxpool(const signed char* __restrict__ in, signed char* __restrict__ out,
                         int N, int H, int W, int C16, int OH, int OW) {
    int idx = blockIdx.x * blockDim.x + threadIdx.x;
    int total = N * OH * OW * C16;
    if (idx >= total) return;
    int cc = idx % C16;
    int t = idx / C16;
    int ox = t % OW; t /= OW;
    int oy = t % OH;
    int n = t / OH;
    const i32x4* ip = (const i32x4*)in;
    int base = ((n * H + oy * 2) * W + ox * 2) * C16 + cc;
    int mb[16];
#pragma unroll
    for (int b = 0; b < 16; ++b) mb[b] = -128;
#pragma unroll
    for (int dy = 0; dy < 3; ++dy)
#pragma unroll
        for (int dx = 0; dx < 3; ++dx) {
            i32x4 v = ip[base + (dy * W + dx) * C16];
#pragma unroll
            for (int d = 0; d < 4; ++d) {
                int u = v[d];
                mb[d * 4 + 0] = max(mb[d * 4 + 0], (int)(signed char)(u & 0xff));
                mb[d * 4 + 1] = max(mb[d * 4 + 1], (int)(signed char)((u >> 8) & 0xff));
                mb[d * 4 + 2] = max(mb[d * 4 + 2], (int)(signed char)((u >> 16) & 0xff));
                mb[d * 4 + 3] = max(mb[d * 4 + 3], (int)(signed char)(u >> 24));
            }
        }
    i32x4 r;
#pragma unroll
    for (int d = 0; d < 4; ++d)
        r[d] = (mb[d * 4 + 0] & 0xff) | ((mb[d * 4 + 1] & 0xff) << 8)
             | ((mb[d * 4 + 2] & 0xff) << 16) | (mb[d * 4 + 3] << 24);
    ((i32x4*)out)[idx] = r;
}

// ---------------- global avg pool over 3x3 + floor: [512,3,3,256] -> [512,256] ----------------
// dword-vectorized: one thread = 4 channels

__global__ void qgap(const signed char* __restrict__ in, signed char* __restrict__ out) {
    int idx = blockIdx.x * blockDim.x + threadIdx.x;
    if (idx >= 512 * 64) return;
    int c4 = idx & 63;
    int n = idx >> 6;
    const int* ip = (const int*)in;
    int s0 = 0, s1 = 0, s2 = 0, s3 = 0;
#pragma unroll
    for (int k = 0; k < 9; ++k) {
        int v = ip[(n * 9 + k) * 64 + c4];
        s0 += (int)(signed char)(v & 0xff);
        s1 += (int)(signed char)((v >> 8) & 0xff);
        s2 += (int)(signed char)((v >> 16) & 0xff);
        s3 += (int)(signed char)(v >> 24);
    }
    // values >= 0 (post-ReLU), so /9 is floor(mean)
    s0 /= 9; s1 /= 9; s2 /= 9; s3 /= 9;
    ((int*)out)[idx] = (s0 & 0xff) | ((s1 & 0xff) << 8) | ((s2 & 0xff) << 16) | (s3 << 24);
}

// ---------------- final FC (no relu), fp32 out: one wave per (b,o), shuffle reduce ----------------

__global__ void qfc3_wave(const signed char* __restrict__ act,
                          const signed char* __restrict__ wq,
                          const int* __restrict__ bias,
                          float* __restrict__ out) {
    int gid = blockIdx.x * blockDim.x + threadIdx.x;
    int wave = gid >> 6;
    int lane = gid & 63;
    if (wave >= 512 * 10) return;
    int o = wave % 10;
    int b = wave / 10;
    const int* aI = (const int*)act + b * 1024;
    const int* wI = (const int*)wq + o * 1024;
    int acc = 0;
#pragma unroll
    for (int it = 0; it < 16; ++it) {
        int k = it * 64 + lane;
        acc = dot4(aI[k], wI[k], acc);
    }
#pragma unroll
    for (int s = 32; s; s >>= 1) acc += __shfl_xor(acc, s);
    if (lane == 0) {
        float v = floorf((float)(acc + bias[o]) * 2e-4f);
        v = fminf(fmaxf(v, -128.0f), 127.0f);
        out[b * 10 + o] = v;
    }
}

// ---------------- launch ----------------

#define LAUNCH(kern, n, ...) kern<<<dim3(((n) + 255) / 256), dim3(256), 0, stream>>>(__VA_ARGS__)

extern "C" void kernel_launch(void* const* d_in, const int* in_sizes, int n_in,
                              void* d_out, int out_size, void* d_ws, size_t ws_size,
                              hipStream_t stream) {
    const float* x   = (const float*)d_in[0];
    const float* w1  = (const float*)d_in[1];
    const float* b1  = (const float*)d_in[2];
    const float* w2  = (const float*)d_in[3];
    const float* b2  = (const float*)d_in[4];
    const float* w3  = (const float*)d_in[5];
    const float* b3  = (const float*)d_in[6];
    const float* w4  = (const float*)d_in[7];
    const float* b4  = (const float*)d_in[8];
    const float* w5  = (const float*)d_in[9];
    const float* b5  = (const float*)d_in[10];
    const float* wf1 = (const float*)d_in[11];
    const float* bf1 = (const float*)d_in[12];
    const float* wf2 = (const float*)d_in[13];
    const float* bf2 = (const float*)d_in[14];
    const float* wf3 = (const float*)d_in[15];
    const float* bf3 = (const float*)d_in[16];
    float* out = (float*)d_out;

    char* ws = (char*)d_ws;
    size_t off = 0;
    auto A = [&](size_t sz) -> size_t {
        size_t o = off;
        off += (sz + 255) & ~(size_t)255;
        return o;
    };

    // fragment-major sizes: (O/32)*KSTEPS*1024
    size_t wq1  = A(96 * 128);
    size_t wq2  = A((size_t)SZ_W2);
    size_t wq3  = A((size_t)SZ_W3);
    size_t wq4  = A((size_t)SZ_W4);
    size_t wq5  = A((size_t)SZ_W5);
    size_t wqf1 = A((size_t)SZ_WF1);
    size_t wqf2 = A((size_t)SZ_WF2);
    size_t wqf3 = A(10 * 4096);
    size_t bq1  = A(96 * 4);
    size_t bq2  = A(256 * 4);
    size_t bq3  = A(384 * 4);
    size_t bq4  = A(384 * 4);
    size_t bq5  = A(256 * 4);
    size_t bqf1 = A(4096 * 4);
    size_t bqf2 = A(4096 * 4);
    size_t bqf3 = A(10 * 4);
    size_t bufA = A(11059200);   // max: pool1 out [512,15,15,96]
    size_t bufB = A(50331648);   // max: conv1 out [512,32,32,96]
    size_t flg  = A(256);        // conversion-cache magic
    if (off > ws_size) return;   // workspace too small — bail rather than corrupt

    signed char* W1 = (signed char*)(ws + wq1);
    signed char* W2 = (signed char*)(ws + wq2);
    signed char* W3 = (signed char*)(ws + wq3);
    signed char* W4 = (signed char*)(ws + wq4);
    signed char* W5 = (signed char*)(ws + wq5);
    signed char* WF1 = (signed char*)(ws + wqf1);
    signed char* WF2 = (signed char*)(ws + wqf2);
    signed char* WF3 = (signed char*)(ws + wqf3);
    int* B1 = (int*)(ws + bq1);
    int* B2 = (int*)(ws + bq2);
    int* B3 = (int*)(ws + bq3);
    int* B4 = (int*)(ws + bq4);
    int* B5 = (int*)(ws + bq5);
    int* BF1 = (int*)(ws + bqf1);
    int* BF2 = (int*)(ws + bqf2);
    int* BF3 = (int*)(ws + bqf3);
    signed char* A_ = (signed char*)(ws + bufA);
    signed char* Bb = (signed char*)(ws + bufB);
    unsigned long long* FLAG = (unsigned long long*)(ws + flg);

    // ---- fused weight/bias conversion (1 launch; early-exits when cache valid) ----
    CvtArgs ca;
    ca.w1 = w1; ca.w2 = w2; ca.w3 = w3; ca.w4 = w4; ca.w5 = w5;
    ca.wf1 = wf1; ca.wf2 = wf2; ca.wf3 = wf3;
    ca.b1 = b1; ca.b2 = b2; ca.b3 = b3; ca.b4 = b4; ca.b5 = b5;
    ca.bf1 = bf1; ca.bf2 = bf2; ca.bf3 = bf3;
    ca.W1 = W1; ca.W2 = W2; ca.W3 = W3; ca.W4 = W4; ca.W5 = W5;
    ca.WF1 = WF1; ca.WF2 = WF2; ca.WF3 = WF3;
    ca.B1 = B1; ca.B2 = B2; ca.B3 = B3; ca.B4 = B4; ca.B5 = B5;
    ca.BF1 = BF1; ca.BF2 = BF2; ca.BF3 = BF3;
    ca.flag = FLAG;
    cvt_all<<<dim3(2048), dim3(256), 0, stream>>>(ca);
    set_flag<<<dim3(1), dim3(1), 0, stream>>>(FLAG);

    // ---- forward ----
    // quantize: x -> A_ [512,32,32,4]
    LAUNCH(quantize_in, 512 * 1024, x, A_, 512 * 1024);

    // conv1 (MFMA + LDS im2col): A_ -> Bb [512,32,32,96]
    conv1_mfma<<<dim3(512 * 1024 / 64), dim3(256), 0, stream>>>(A_, W1, B1, Bb);

    // pool1: Bb -> A_ [512,15,15,96]; C16=6
    LAUNCH(qmaxpool, 512 * 15 * 15 * 6, Bb, A_, 512, 32, 32, 6, 15, 15);

    // conv2: A_ -> Bb [512,15,15,256]; 8-wave shared-B, OCT=8; 3-buf LDS 72 KB (champion)
    conv_mfma32<5, 96, 8, 1, 3, 8, 2><<<dim3(450, 1), dim3(512), 0, stream>>>(
        A_, W2, B2, Bb, 15, 15, 15, 15, 256, 2, 4e-4f);

    // pool2: Bb -> A_ [512,7,7,256]; C16=16
    LAUNCH(qmaxpool, 512 * 7 * 7 * 16, Bb, A_, 512, 15, 15, 16, 7, 7);

    // conv3: A_ -> Bb [512,7,7,384]; 8-wave: OCT=6, GSTEP=4 (SUBG=2); 3-buf LDS 72 KB
    conv_mfma32<3, 256, 6, 1, 4, 8, 2><<<dim3(98, 2), dim3(512), 0, stream>>>(
        A_, W3, B3, Bb, 7, 7, 7, 7, 384, 1, 2e-4f);

    // conv4: Bb -> A_ [512,7,7,384]; 8-wave: OCT=6, GSTEP=4 (SUBG=3); 3-buf LDS 72 KB
    conv_mfma32<3, 384, 6, 1, 4, 8, 2><<<dim3(98, 2), dim3(512), 0, stream>>>(
        Bb, W4, B4, A_, 7, 7, 7, 7, 384, 1, 2e-4f);

    // conv5: A_ -> Bb [512,7,7,256]; 8-wave: OCT=4, GSTEP=6 (SUBG=2); 3-buf LDS 72 KB
    conv_mfma32<3, 384, 4, 1, 6, 8, 2><<<dim3(98, 2), dim3(512), 0, stream>>>(
        A_, W5, B5, Bb, 7, 7, 7, 7, 256, 1, 2e-4f);

    // pool3: Bb -> A_ [512,3,3,256]; C16=16
    LAUNCH(qmaxpool, 512 * 3 * 3 * 16, Bb, A_, 512, 7, 7, 16, 3, 3);

    // gap: A_ -> Bb [512,256]; dword-vectorized
    LAUNCH(qgap, 512 * 64, A_, Bb);

    // fc1: Bb -> A_ [512,4096]; OCT=1 -> 512 blocks = 2 waves/SIMD; NG=1; LDS 8 KB
    conv_mfma32<1, 256, 1, 1, 8, 4, 2><<<dim3(4, 128), dim3(256), 0, stream>>>(
        Bb, WF1, BF1, A_, 1, 1, 1, 1, 4096, 0, 1e-3f);

    // fc2: A_ -> Bb [512,4096]; OCT=1 -> 512 blocks = 2 waves/SIMD; NG=16; 3-buf LDS 24 KB
    conv_mfma32<1, 4096, 1, 1, 8, 4, 2><<<dim3(4, 128), dim3(256), 0, stream>>>(
        A_, WF2, BF2, Bb, 1, 1, 1, 1, 4096, 0, 2e-4f);

    // fc3: Bb -> out [512,10] fp32; one wave per output
    qfc3_wave<<<dim3(512 * 10 * 64 / 256), dim3(256), 0, stream>>>(Bb, WF3, BF3, out);
}

// Round 12
// 487.902 us; speedup vs baseline: 1.0325x; 1.0325x over previous
//
#include <hip/hip_runtime.h>

#define DEV_INLINE __device__ __forceinline__

typedef int i32x4 __attribute__((ext_vector_type(4)));
typedef int i32x16 __attribute__((ext_vector_type(16)));

DEV_INLINE int dot4(int a, int b, int c) {
#if __has_builtin(__builtin_amdgcn_sdot4)
    return __builtin_amdgcn_sdot4(a, b, c, false);
#else
    return c
        + (int)(signed char)(a)       * (int)(signed char)(b)
        + (int)(signed char)(a >> 8)  * (int)(signed char)(b >> 8)
        + (int)(signed char)(a >> 16) * (int)(signed char)(b >> 16)
        + (int)(signed char)(a >> 24) * (int)(signed char)(b >> 24);
#endif
}

typedef __attribute__((address_space(1))) const unsigned int guint;
typedef __attribute__((address_space(3))) unsigned int luint;

// async 16B/lane global->LDS DMA: lane i's 16B from g+lane*16 lands at l+lane*16
DEV_INLINE void async_cp16(const signed char* g, signed char* l) {
    __builtin_amdgcn_global_load_lds((guint*)g, (luint*)l, 16, 0, 0);
}

// counted-vmcnt barrier: wait until <=N vector-memory ops outstanding, then s_barrier.
template <int N>
DEV_INLINE void wait_barrier() {
    __builtin_amdgcn_sched_barrier(0);
    asm volatile("s_waitcnt vmcnt(%0)" :: "n"(N) : "memory");
    __builtin_amdgcn_s_barrier();
    __builtin_amdgcn_sched_barrier(0);
}

// ---------------- fused weight/bias conversion (single launch, ws-cached) ----------------

#define CVT_MAGIC 0x9E3779B97F4A7C15ull

// Repack to 32-wide MFMA B-fragment-major order, K reordered tap-major:
//   step = tap*CP + cpair;  lane holds B[n = oc%32][element c = cpair*32 + (lane>>5)*16 + j of tap]
DEV_INLINE void cvt_frag32_elem(const float* __restrict__ w, signed char* __restrict__ o,
                                int idx, int I, int KK, int CP, int KSTEPS) {
    int j = idx & 15;
    int lane = (idx >> 4) & 63;
    int step = (idx >> 10) % KSTEPS;
    int tile = idx / (KSTEPS << 10);
    int oc = tile * 32 + (lane & 31);
    int tap = step / CP;
    int cpair = step - tap * CP;
    int c = cpair * 32 + ((lane >> 5) << 4) + j;
    o[idx] = (signed char)(int)w[((size_t)oc * I + c) * KK + tap];
}

struct CvtArgs {
    const float *w1, *w2, *w3, *w4, *w5, *wf1, *wf2, *wf3;
    const float *b1, *b2, *b3, *b4, *b5, *bf1, *bf2, *bf3;
    signed char *W1, *W2, *W3, *W4, *W5, *WF1, *WF2, *WF3;
    int *B1, *B2, *B3, *B4, *B5, *BF1, *BF2, *BF3;
    const unsigned long long* flag;
};

#define SZ_W2  (8 * 75 * 1024)
#define SZ_W3  (12 * 72 * 1024)
#define SZ_W4  (12 * 108 * 1024)
#define SZ_W5  (8 * 108 * 1024)
#define SZ_WF1 (128 * 8 * 1024)
#define SZ_WF2 (128 * 128 * 1024)
#define SZ_WF3 (10 * 4096)
#define SZ_W1  (96 * 128)
#define SZ_BIAS (96 + 256 + 384 + 384 + 256 + 4096 + 4096 + 10)
#define CVT_TOTAL (SZ_WF2 + SZ_W4 + SZ_WF1 + SZ_W3 + SZ_W5 + SZ_W2 + SZ_WF3 + SZ_W1 + SZ_BIAS)

DEV_INLINE void cvt_one(const CvtArgs& a, int idx) {
    if (idx < SZ_WF2) { cvt_frag32_elem(a.wf2, a.WF2, idx, 4096, 1, 128, 128); return; }
    idx -= SZ_WF2;
    if (idx < SZ_W4) { cvt_frag32_elem(a.w4, a.W4, idx, 384, 9, 12, 108); return; }
    idx -= SZ_W4;
    if (idx < SZ_WF1) { cvt_frag32_elem(a.wf1, a.WF1, idx, 256, 1, 8, 8); return; }
    idx -= SZ_WF1;
    if (idx < SZ_W3) { cvt_frag32_elem(a.w3, a.W3, idx, 256, 9, 8, 72); return; }
    idx -= SZ_W3;
    if (idx < SZ_W5) { cvt_frag32_elem(a.w5, a.W5, idx, 384, 9, 12, 108); return; }
    idx -= SZ_W5;
    if (idx < SZ_W2) { cvt_frag32_elem(a.w2, a.W2, idx, 96, 25, 3, 75); return; }
    idx -= SZ_W2;
    if (idx < SZ_WF3) { a.WF3[idx] = (signed char)(int)a.wf3[idx]; return; }
    idx -= SZ_WF3;
    if (idx < SZ_W1) {
        // conv1 weights: OIHW [96][3][5][5] fp32 -> [96][128] int8, byte [oc][tap*4+c]
        int b = idx & 127;
        int oc = idx >> 7;
        int tap = b >> 2;
        int c = b & 3;
        float v = (tap < 25 && c < 3) ? a.w1[(oc * 3 + c) * 25 + tap] : 0.0f;
        a.W1[idx] = (signed char)(int)v;
        return;
    }
    idx -= SZ_W1;
    if (idx < 96) { a.B1[idx] = (int)a.b1[idx]; return; } idx -= 96;
    if (idx < 256) { a.B2[idx] = (int)a.b2[idx]; return; } idx -= 256;
    if (idx < 384) { a.B3[idx] = (int)a.b3[idx]; return; } idx -= 384;
    if (idx < 384) { a.B4[idx] = (int)a.b4[idx]; return; } idx -= 384;
    if (idx < 256) { a.B5[idx] = (int)a.b5[idx]; return; } idx -= 256;
    if (idx < 4096) { a.BF1[idx] = (int)a.bf1[idx]; return; } idx -= 4096;
    if (idx < 4096) { a.BF2[idx] = (int)a.bf2[idx]; return; } idx -= 4096;
    if (idx < 10) { a.BF3[idx] = (int)a.bf3[idx]; }
}

// grid-stride: cheap early-exit when the ws cache flag is valid
__global__ void cvt_all(CvtArgs a) {
    if (*a.flag == CVT_MAGIC) return;
    int stride = gridDim.x * blockDim.x;
    for (int idx = blockIdx.x * blockDim.x + threadIdx.x; idx < CVT_TOTAL; idx += stride)
        cvt_one(a, idx);
}

__global__ void set_flag(unsigned long long* f) { *f = CVT_MAGIC; }

// ---------------- quantize input: NCHW fp32 [512,3,32,32] -> NHWC int8 [512,32,32,4] ----------------

__global__ void quantize_in(const float* __restrict__ x, signed char* __restrict__ q, int total) {
    int idx = blockIdx.x * blockDim.x + threadIdx.x;
    if (idx >= total) return;                 // total = 512*32*32
    int hw = idx & 1023;
    int n = idx >> 10;
    const float* xp = x + n * 3072 + hw;
    int b[4];
#pragma unroll
    for (int c = 0; c < 3; ++c) {
        float v = rintf(xp[c * 1024] / 0.05f);
        v = fminf(fmaxf(v, -128.0f), 127.0f);
        b[c] = (int)v;
    }
    b[3] = 0;
    int packed = (b[0] & 0xff) | ((b[1] & 0xff) << 8) | ((b[2] & 0xff) << 16) | (b[3] << 24);
    ((int*)q)[idx] = packed;
}

// ---------------- conv1 MFMA with LDS im2col (16x16x64 path, Cin=4) ----------------
// im2col site stride padded 36 -> 37 dwords (2-way bank aliasing, free).
// Epilogue (this revision): requantized bytes staged in LDS ([64 sites][96B] @112B
// stride), then 256 threads store the 6 KB block as coalesced dwords (6 x 1KB/instr)
// -- replaces 24 scattered byte-stores/lane (64B/instr) with dense dword stores.

__global__ void conv1_mfma(const signed char* __restrict__ act,
                           const signed char* __restrict__ wq,
                           const int* __restrict__ bias,
                           signed char* __restrict__ out) {
    __shared__ int lds[64 * 37];                  // 9472 B: im2col, then reused as out-stage (7168 B)

    int tid = threadIdx.x;
    int lane = tid & 63;
    int wid = tid >> 6;
    int siteBase = blockIdx.x * 64;

    {
        int site_local = tid >> 2;
        int g = tid & 3;
        int site = siteBase + site_local;
        int ox = site & 31;
        int oy = (site >> 5) & 31;
        int n = site >> 10;
        const int* aI = (const int*)act;
        int* dst = lds + site_local * 37 + g * 8;
#pragma unroll
        for (int j = 0; j < 8; ++j) {
            int tap = g * 8 + j;
            int v = 0;
            if (tap < 25) {
                int ky = tap / 5;
                int kx = tap - ky * 5;
                int iy = oy - 2 + ky;
                int ix = ox - 2 + kx;
                if ((unsigned)iy < 32u && (unsigned)ix < 32u)
                    v = aI[(n << 10) + (iy << 5) + ix];
            }
            dst[j] = v;
        }
    }

    int m = lane & 15;
    int q = lane >> 4;

    i32x4 bfrag[6][2];
#pragma unroll
    for (int j = 0; j < 6; ++j)
#pragma unroll
        for (int s = 0; s < 2; ++s)
            bfrag[j][s] = *(const i32x4*)(wq + (j * 16 + m) * 128 + s * 64 + q * 16);

    i32x4 acc[6];
#pragma unroll
    for (int j = 0; j < 6; ++j) {
        int bv = bias[j * 16 + m];
        acc[j] = (i32x4){bv, bv, bv, bv};
    }

    __syncthreads();

#pragma unroll
    for (int s = 0; s < 2; ++s) {
        const int* ap = lds + (wid * 16 + m) * 37 + s * 16 + q * 4;
        i32x4 a = (i32x4){ap[0], ap[1], ap[2], ap[3]};
#pragma unroll
        for (int j = 0; j < 6; ++j)
            acc[j] = __builtin_amdgcn_mfma_i32_16x16x64_i8(a, bfrag[j][s], acc[j], 0, 0, 0);
    }

    __syncthreads();                              // all im2col LDS reads complete

    // stage requantized bytes: lout[site][oc], stride 112 B (28 dwords; 2-way aliasing)
    signed char* lout = (signed char*)lds;
#pragma unroll
    for (int j = 0; j < 6; ++j) {
        int oc = j * 16 + m;
#pragma unroll
        for (int r = 0; r < 4; ++r) {
            int site_l = wid * 16 + q * 4 + r;
            float v = floorf((float)acc[j][r] * 2e-3f);
            v = fminf(fmaxf(v, 0.0f), 127.0f);
            lout[site_l * 112 + oc] = (signed char)v;
        }
    }

    __syncthreads();

    // coalesced block store: 64 sites x 96 B = 1536 dwords, 6 per thread
    int* og = (int*)(out + (size_t)siteBase * 96);
#pragma unroll
    for (int i = 0; i < 6; ++i) {
        int d = tid + i * 256;
        int site = d / 24;
        int rem = d - site * 24;
        og[d] = lds[site * 28 + rem];
    }
}

// ---------------- implicit-GEMM 32x32x32 MFMA conv (also FC), LDS-staged B ----------------
// act: NHWC int8 (Cin multiple of 32), wqf: fragment-major [Cout/32][KSTEPS][64][16],
// K tap-major (step = tap*CP + cpair). Block = WAVES waves, ALL sharing one staged B
// range (OCT oc-tiles); each wave owns SITES site-tiles. Groups may be a SUB-TAP slice
// (SUBG = CP/GSTEP slices per tap) to shrink LDS.
//
// DEPTH-2 PREFETCH: triple-buffered LDS; stage(g+2) issued at cp0 of group g, so the
// end-of-g barrier's wait for stage(g+1) has ~2 full groups of MFMA cover. Counted
// waits (in-order vmcnt retirement):
//   NSTEADY = (2*GSTEP-1)*SITES + UNITS/WAVES  (ops younger than stage(g+1)'s DMAs)
//   NTAIL   = (2*GSTEP-1)*SITES                (last staged group: no stage in body)
// Issue order and A-load clamping are byte-identical to the verified round-7 skeleton.
// 8-wave shared-B geometry (conv2-5): B-transit 1024/(WAVES*SITES)=128 B/MFMA,
// A-transit 1024/OCT.

template <int KS, int CIN, int OCT, int SITES, int GSTEP, int WAVES, int MINW>
__launch_bounds__(WAVES * 64, MINW)
__global__ void conv_mfma32(const signed char* __restrict__ act,
                            const signed char* __restrict__ wqf,
                            const int* __restrict__ bias,
                            signed char* __restrict__ out,
                            int H, int W, int OH, int OW, int Cout, int pad, float M) {
    constexpr int CP = CIN / 32;
    constexpr int KSTEPS = KS * KS * CP;
    constexpr int NG = KSTEPS / GSTEP;
    constexpr int SUBG = CP / GSTEP;              // sub-tap slices per tap
    constexpr int CHUNK = OCT * GSTEP * 1024;
    constexpr int UNITS = OCT * GSTEP;
    constexpr int NBUF = (NG >= 3) ? 3 : NG;      // depth-2 prefetch needs 3 buffers
    constexpr int DW = UNITS / WAVES;             // floor: safe lower bound per wave
    constexpr int NSTEADY = (2 * GSTEP - 1) * SITES + DW;
    constexpr int NTAIL = (2 * GSTEP - 1) * SITES;
    constexpr int NPRO = SITES + ((NG > 1) ? DW : 0);
    static_assert(CIN % 32 == 0, "CIN must be multiple of 32");
    static_assert(CP % GSTEP == 0, "GSTEP must divide CP (sub-tap slicing)");
    static_assert(KSTEPS % GSTEP == 0, "GSTEP must divide KSTEPS");
    static_assert(NG != 2, "NG==2 barrier count unsupported");
    static_assert(NSTEADY <= 63, "vmcnt immediate range");

    __shared__ signed char lds[NBUF * CHUNK];

    int lane = threadIdx.x & 63;
    int wid = threadIdx.x >> 6;
    int m32 = lane & 31;
    int q2 = lane >> 5;                           // 0/1: k-half
    int waveBase = blockIdx.x * (SITES * 32 * WAVES) + wid * (SITES * 32);
    int oc0 = blockIdx.y * (OCT * 32);

    const signed char* wblk = wqf + (size_t)(blockIdx.y * OCT) * KSTEPS * 1024;
    const signed char* actq = act + q2 * 16;

    // async-stage group g's B fragments into buffer `buf` (split across WAVES waves)
    auto stage = [&](int buf, int g) {
#pragma unroll
        for (int t = 0; t < (UNITS + WAVES - 1) / WAVES; ++t) {
            int u = t * WAVES + wid;              // 1KB unit: u = j*GSTEP + s
            if (UNITS % WAVES == 0 || u < UNITS) {
                int j = u / GSTEP;
                int s = u - j * GSTEP;
                const signed char* gsrc =
                    wblk + (((size_t)(j * KSTEPS + g * GSTEP + s)) << 10) + lane * 16;
                async_cp16(gsrc, lds + buf * CHUNK + (u << 10));
            }
        }
        __builtin_amdgcn_sched_barrier(0);        // nothing issued later may get older than DMAs
    };

    stage(0, 0);                                  // FIRST vm ops of the kernel

    // per-site-tile coordinate decode (A-side lane site); 32-bit offsets
    int oxA[SITES], oyA[SITES], rbA[SITES];
#pragma unroll
    for (int s = 0; s < SITES; ++s) {
        int site = waveBase + s * 32 + m32;
        int ox = site % OW;
        int t = site / OW;
        oxA[s] = ox;
        oyA[s] = t % OH;
        rbA[s] = (t / OH) * H;
    }

    i32x16 acc[SITES][OCT];
#pragma unroll
    for (int j = 0; j < OCT; ++j) {
        int bv = bias[oc0 + j * 32 + m32];
#pragma unroll
        for (int s = 0; s < SITES; ++s)
#pragma unroll
            for (int r = 0; r < 16; ++r)
                acc[s][j][r] = bv;
    }

    // A-side byte offsets (from actq) + validity for group g (tap = g/SUBG, sub-slice)
    auto calcOff = [&](int g, int* off, bool* ok) {
        int tap = g / SUBG;
        int sub = g - tap * SUBG;
        int ty, tx;
        if constexpr (KS == 1) { ty = 0; tx = 0; }
        else { ty = tap / KS; tx = tap - ty * KS; }
#pragma unroll
        for (int s = 0; s < SITES; ++s) {
            int iy = oyA[s] - pad + ty;
            int ix = oxA[s] - pad + tx;
            if constexpr (KS == 1) ok[s] = true;
            else ok[s] = ((unsigned)iy < (unsigned)H) && ((unsigned)ix < (unsigned)W);
            off[s] = ((rbA[s] + iy) * W + ix) * CIN + sub * (GSTEP * 32);
        }
    };

    // UNCONDITIONAL load (clamped offset, select-zero): vm-op count is compile-time exact
    auto loadA = [&](i32x4* a, const int* off, const bool* ok, int cp) {
#pragma unroll
        for (int s = 0; s < SITES; ++s) {
            int o = ok[s] ? off[s] + cp * 32 : 0;
            i32x4 v = *(const i32x4*)(actq + o);
            a[s] = ok[s] ? v : (i32x4){0, 0, 0, 0};
        }
    };

    int offC[SITES], offN[SITES];
    bool okC[SITES], okN[SITES];
    i32x4 aC[SITES], aN[SITES];
#pragma unroll
    for (int s = 0; s < SITES; ++s) {
        aN[s] = (i32x4){0, 0, 0, 0};
        offN[s] = 0;
        okN[s] = false;
    }

    calcOff(0, offC, okC);
    loadA(aC, offC, okC, 0);                      // SITES loads, younger than stage(0)
    if constexpr (NG > 1) stage(1 % NBUF, 1);     // depth-2 prologue

    wait_barrier<NPRO>();                         // drains stage(0) only

    for (int g = 0; g < NG; ++g) {
        const signed char* lb = lds + (g % NBUF) * CHUNK + lane * 16;
#pragma unroll
        for (int cp = 0; cp < GSTEP; ++cp) {
            // fresh per-cp B fragments (compiler schedules fine-grained lgkm waits)
            i32x4 b[OCT];
#pragma unroll
            for (int j = 0; j < OCT; ++j)
                b[j] = *(const i32x4*)(lb + ((j * GSTEP + cp) << 10));
            // prefetch next A slice: cp0's issue is BEFORE this group's stage DMAs
            if (cp + 1 < GSTEP)
                loadA(aN, offC, okC, cp + 1);
            if (cp == 0) {
                if (g + 2 < NG) stage((g + 2) % NBUF, g + 2);   // 2-group-deep prefetch
                if (g + 1 < NG) calcOff(g + 1, offN, okN);      // VALU, overlaps MFMAs
            }
            if (cp + 1 == GSTEP && g + 1 < NG)
                loadA(aN, offN, okN, 0);          // (g+1, cp0): stays in flight across barrier
#pragma unroll
            for (int j = 0; j < OCT; ++j)
#pragma unroll
                for (int s = 0; s < SITES; ++s)
                    acc[s][j] = __builtin_amdgcn_mfma_i32_32x32x32_i8(aC[s], b[j], acc[s][j], 0, 0, 0);
#pragma unroll
            for (int s = 0; s < SITES; ++s) aC[s] = aN[s];
        }
#pragma unroll
        for (int s = 0; s < SITES; ++s) { offC[s] = offN[s]; okC[s] = okN[s]; }
        if (g + 2 < NG)
            wait_barrier<NSTEADY>();              // stage(g+1) drained; ~2 groups of cover
        else if (g + 1 < NG)
            wait_barrier<NTAIL>();                // last staged group (no stage in body)
    }

    // D layout: col(oc) = lane&31, row(site) = (r&3) + 8*(r>>2) + 4*q2
#pragma unroll
    for (int s = 0; s < SITES; ++s) {
#pragma unroll
        for (int j = 0; j < OCT; ++j) {
            int oc = oc0 + j * 32 + m32;
#pragma unroll
            for (int r = 0; r < 16; ++r) {
                int row = (r & 3) + 8 * (r >> 2) + 4 * q2;
                int site = waveBase + s * 32 + row;
                float v = floorf((float)acc[s][j][r] * M);
                v = fminf(fmaxf(v, 0.0f), 127.0f);
                out[(size_t)site * Cout + oc] = (signed char)v;
            }
        }
    }
}

// ---------------- maxpool 3x3 stride 2, NHWC, 16 channels (i32x4) per thread ----------------

__global__ void qmaxpool(const signed char* __restrict__ in, signed char* __restrict__ out,
                         int N, int H, int W, int C16, int OH, int OW) {
    int idx = blockIdx.x * blockDim.x + threadIdx.x;
    int total = N * OH * OW * C16;
    if (idx >= total) return;
    int cc = idx % C16;
    int t = idx / C16;
    int ox = t % OW; t /= OW;
    int oy = t % OH;
    int n = t / OH;
    const i32x4* ip = (const i32x4*)in;
    int base = ((n * H + oy * 2) * W + ox * 2) * C16 + cc;
    int mb[16];
#pragma unroll
    for (int b = 0; b < 16; ++b) mb[b] = -128;
#pragma unroll
    for (int dy = 0; dy < 3; ++dy)
#pragma unroll
        for (int dx = 0; dx < 3; ++dx) {
            i32x4 v = ip[base + (dy * W + dx) * C16];
#pragma unroll
            for (int d = 0; d < 4; ++d) {
                int u = v[d];
                mb[d * 4 + 0] = max(mb[d * 4 + 0], (int)(signed char)(u & 0xff));
                mb[d * 4 + 1] = max(mb[d * 4 + 1], (int)(signed char)((u >> 8) & 0xff));
                mb[d * 4 + 2] = max(mb[d * 4 + 2], (int)(signed char)((u >> 16) & 0xff));
                mb[d * 4 + 3] = max(mb[d * 4 + 3], (int)(signed char)(u >> 24));
            }
        }
    i32x4 r;
#pragma unroll
    for (int d = 0; d < 4; ++d)
        r[d] = (mb[d * 4 + 0] & 0xff) | ((mb[d * 4 + 1] & 0xff) << 8)
             | ((mb[d * 4 + 2] & 0xff) << 16) | (mb[d * 4 + 3] << 24);
    ((i32x4*)out)[idx] = r;
}

// ---------------- global avg pool over 3x3 + floor: [512,3,3,256] -> [512,256] ----------------
// dword-vectorized: one thread = 4 channels

__global__ void qgap(const signed char* __restrict__ in, signed char* __restrict__ out) {
    int idx = blockIdx.x * blockDim.x + threadIdx.x;
    if (idx >= 512 * 64) return;
    int c4 = idx & 63;
    int n = idx >> 6;
    const int* ip = (const int*)in;
    int s0 = 0, s1 = 0, s2 = 0, s3 = 0;
#pragma unroll
    for (int k = 0; k < 9; ++k) {
        int v = ip[(n * 9 + k) * 64 + c4];
        s0 += (int)(signed char)(v & 0xff);
        s1 += (int)(signed char)((v >> 8) & 0xff);
        s2 += (int)(signed char)((v >> 16) & 0xff);
        s3 += (int)(signed char)(v >> 24);
    }
    // values >= 0 (post-ReLU), so /9 is floor(mean)
    s0 /= 9; s1 /= 9; s2 /= 9; s3 /= 9;
    ((int*)out)[idx] = (s0 & 0xff) | ((s1 & 0xff) << 8) | ((s2 & 0xff) << 16) | (s3 << 24);
}

// ---------------- final FC (no relu), fp32 out: one wave per (b,o), shuffle reduce ----------------

__global__ void qfc3_wave(const signed char* __restrict__ act,
                          const signed char* __restrict__ wq,
                          const int* __restrict__ bias,
                          float* __restrict__ out) {
    int gid = blockIdx.x * blockDim.x + threadIdx.x;
    int wave = gid >> 6;
    int lane = gid & 63;
    if (wave >= 512 * 10) return;
    int o = wave % 10;
    int b = wave / 10;
    const int* aI = (const int*)act + b * 1024;
    const int* wI = (const int*)wq + o * 1024;
    int acc = 0;
#pragma unroll
    for (int it = 0; it < 16; ++it) {
        int k = it * 64 + lane;
        acc = dot4(aI[k], wI[k], acc);
    }
#pragma unroll
    for (int s = 32; s; s >>= 1) acc += __shfl_xor(acc, s);
    if (lane == 0) {
        float v = floorf((float)(acc + bias[o]) * 2e-4f);
        v = fminf(fmaxf(v, -128.0f), 127.0f);
        out[b * 10 + o] = v;
    }
}

// ---------------- launch ----------------

#define LAUNCH(kern, n, ...) kern<<<dim3(((n) + 255) / 256), dim3(256), 0, stream>>>(__VA_ARGS__)

extern "C" void kernel_launch(void* const* d_in, const int* in_sizes, int n_in,
                              void* d_out, int out_size, void* d_ws, size_t ws_size,
                              hipStream_t stream) {
    const float* x   = (const float*)d_in[0];
    const float* w1  = (const float*)d_in[1];
    const float* b1  = (const float*)d_in[2];
    const float* w2  = (const float*)d_in[3];
    const float* b2  = (const float*)d_in[4];
    const float* w3  = (const float*)d_in[5];
    const float* b3  = (const float*)d_in[6];
    const float* w4  = (const float*)d_in[7];
    const float* b4  = (const float*)d_in[8];
    const float* w5  = (const float*)d_in[9];
    const float* b5  = (const float*)d_in[10];
    const float* wf1 = (const float*)d_in[11];
    const float* bf1 = (const float*)d_in[12];
    const float* wf2 = (const float*)d_in[13];
    const float* bf2 = (const float*)d_in[14];
    const float* wf3 = (const float*)d_in[15];
    const float* bf3 = (const float*)d_in[16];
    float* out = (float*)d_out;

    char* ws = (char*)d_ws;
    size_t off = 0;
    auto A = [&](size_t sz) -> size_t {
        size_t o = off;
        off += (sz + 255) & ~(size_t)255;
        return o;
    };

    // fragment-major sizes: (O/32)*KSTEPS*1024
    size_t wq1  = A(96 * 128);
    size_t wq2  = A((size_t)SZ_W2);
    size_t wq3  = A((size_t)SZ_W3);
    size_t wq4  = A((size_t)SZ_W4);
    size_t wq5  = A((size_t)SZ_W5);
    size_t wqf1 = A((size_t)SZ_WF1);
    size_t wqf2 = A((size_t)SZ_WF2);
    size_t wqf3 = A(10 * 4096);
    size_t bq1  = A(96 * 4);
    size_t bq2  = A(256 * 4);
    size_t bq3  = A(384 * 4);
    size_t bq4  = A(384 * 4);
    size_t bq5  = A(256 * 4);
    size_t bqf1 = A(4096 * 4);
    size_t bqf2 = A(4096 * 4);
    size_t bqf3 = A(10 * 4);
    size_t bufA = A(11059200);   // max: pool1 out [512,15,15,96]
    size_t bufB = A(50331648);   // max: conv1 out [512,32,32,96]
    size_t flg  = A(256);        // conversion-cache magic
    if (off > ws_size) return;   // workspace too small — bail rather than corrupt

    signed char* W1 = (signed char*)(ws + wq1);
    signed char* W2 = (signed char*)(ws + wq2);
    signed char* W3 = (signed char*)(ws + wq3);
    signed char* W4 = (signed char*)(ws + wq4);
    signed char* W5 = (signed char*)(ws + wq5);
    signed char* WF1 = (signed char*)(ws + wqf1);
    signed char* WF2 = (signed char*)(ws + wqf2);
    signed char* WF3 = (signed char*)(ws + wqf3);
    int* B1 = (int*)(ws + bq1);
    int* B2 = (int*)(ws + bq2);
    int* B3 = (int*)(ws + bq3);
    int* B4 = (int*)(ws + bq4);
    int* B5 = (int*)(ws + bq5);
    int* BF1 = (int*)(ws + bqf1);
    int* BF2 = (int*)(ws + bqf2);
    int* BF3 = (int*)(ws + bqf3);
    signed char* A_ = (signed char*)(ws + bufA);
    signed char* Bb = (signed char*)(ws + bufB);
    unsigned long long* FLAG = (unsigned long long*)(ws + flg);

    // ---- fused weight/bias conversion (1 launch; early-exits when cache valid) ----
    CvtArgs ca;
    ca.w1 = w1; ca.w2 = w2; ca.w3 = w3; ca.w4 = w4; ca.w5 = w5;
    ca.wf1 = wf1; ca.wf2 = wf2; ca.wf3 = wf3;
    ca.b1 = b1; ca.b2 = b2; ca.b3 = b3; ca.b4 = b4; ca.b5 = b5;
    ca.bf1 = bf1; ca.bf2 = bf2; ca.bf3 = bf3;
    ca.W1 = W1; ca.W2 = W2; ca.W3 = W3; ca.W4 = W4; ca.W5 = W5;
    ca.WF1 = WF1; ca.WF2 = WF2; ca.WF3 = WF3;
    ca.B1 = B1; ca.B2 = B2; ca.B3 = B3; ca.B4 = B4; ca.B5 = B5;
    ca.BF1 = BF1; ca.BF2 = BF2; ca.BF3 = BF3;
    ca.flag = FLAG;
    cvt_all<<<dim3(2048), dim3(256), 0, stream>>>(ca);
    set_flag<<<dim3(1), dim3(1), 0, stream>>>(FLAG);

    // ---- forward ----
    // quantize: x -> A_ [512,32,32,4]
    LAUNCH(quantize_in, 512 * 1024, x, A_, 512 * 1024);

    // conv1 (MFMA + LDS im2col + coalesced dword epilogue): A_ -> Bb [512,32,32,96]
    conv1_mfma<<<dim3(512 * 1024 / 64), dim3(256), 0, stream>>>(A_, W1, B1, Bb);

    // pool1: Bb -> A_ [512,15,15,96]; C16=6
    LAUNCH(qmaxpool, 512 * 15 * 15 * 6, Bb, A_, 512, 32, 32, 6, 15, 15);

    // conv2: A_ -> Bb [512,15,15,256]; 8-wave shared-B, OCT=8; 3-buf LDS 72 KB (champion)
    conv_mfma32<5, 96, 8, 1, 3, 8, 2><<<dim3(450, 1), dim3(512), 0, stream>>>(
        A_, W2, B2, Bb, 15, 15, 15, 15, 256, 2, 4e-4f);

    // pool2: Bb -> A_ [512,7,7,256]; C16=16
    LAUNCH(qmaxpool, 512 * 7 * 7 * 16, Bb, A_, 512, 15, 15, 16, 7, 7);

    // conv3: A_ -> Bb [512,7,7,384]; 8-wave: OCT=6, GSTEP=4 (SUBG=2); 3-buf LDS 72 KB
    conv_mfma32<3, 256, 6, 1, 4, 8, 2><<<dim3(98, 2), dim3(512), 0, stream>>>(
        A_, W3, B3, Bb, 7, 7, 7, 7, 384, 1, 2e-4f);

    // conv4: Bb -> A_ [512,7,7,384]; 8-wave: OCT=6, GSTEP=4 (SUBG=3); 3-buf LDS 72 KB
    conv_mfma32<3, 384, 6, 1, 4, 8, 2><<<dim3(98, 2), dim3(512), 0, stream>>>(
        Bb, W4, B4, A_, 7, 7, 7, 7, 384, 1, 2e-4f);

    // conv5: A_ -> Bb [512,7,7,256]; 8-wave: OCT=4, GSTEP=6 (SUBG=2); 3-buf LDS 72 KB
    conv_mfma32<3, 384, 4, 1, 6, 8, 2><<<dim3(98, 2), dim3(512), 0, stream>>>(
        A_, W5, B5, Bb, 7, 7, 7, 7, 256, 1, 2e-4f);

    // pool3: Bb -> A_ [512,3,3,256]; C16=16
    LAUNCH(qmaxpool, 512 * 3 * 3 * 16, Bb, A_, 512, 7, 7, 16, 3, 3);

    // gap: A_ -> Bb [512,256]; dword-vectorized
    LAUNCH(qgap, 512 * 64, A_, Bb);

    // fc1: Bb -> A_ [512,4096]; OCT=2 (round-10 proven); grid (4,64); LDS 16 KB
    conv_mfma32<1, 256, 2, 1, 8, 4, 2><<<dim3(4, 64), dim3(256), 0, stream>>>(
        Bb, WF1, BF1, A_, 1, 1, 1, 1, 4096, 0, 1e-3f);

    // fc2: A_ -> Bb [512,4096]; OCT=2 (round-10 proven); grid (4,64); 3-buf LDS 48 KB
    conv_mfma32<1, 4096, 2, 1, 8, 4, 2><<<dim3(4, 64), dim3(256), 0, stream>>>(
        A_, WF2, BF2, Bb, 1, 1, 1, 1, 4096, 0, 2e-4f);

    // fc3: Bb -> out [512,10] fp32; one wave per output
    qfc3_wave<<<dim3(512 * 10 * 64 / 256), dim3(256), 0, stream>>>(Bb, WF3, BF3, out);
}